// Round 1
// baseline (1296.444 us; speedup 1.0000x reference)
//
#include <hip/hip_runtime.h>
#include <cstdint>

// Fast activations: ~2-ulp exp/div is plenty vs the 1e-3 absmax threshold.
__device__ __forceinline__ float fsig(float x) {
  x = fminf(fmaxf(x, -30.f), 30.f);
  return __fdividef(1.f, 1.f + __expf(-x));
}
__device__ __forceinline__ float ftanh_(float x) {
  x = fminf(fmaxf(x, -15.f), 15.f);
  float e = __expf(2.f * x);
  return __fdividef(e - 1.f, e + 1.f);
}

// ---------------------------------------------------------------------------
// Layer 1: 262144 independent LSTM chains, seq=16, input=1, hidden=8.
// One chain per thread. Weights broadcast from LDS (uniform addr = no conflict).
// ---------------------------------------------------------------------------
__global__ __launch_bounds__(256) void lstm1_kernel(
    const float* __restrict__ x, const float* __restrict__ Wih,
    const float* __restrict__ Whh, const float* __restrict__ bih,
    const float* __restrict__ bhh, float* __restrict__ h1) {
  __shared__ float sWih[32], sB[32], sWhh[256];
  const int tid = threadIdx.x;
  if (tid < 32) { sWih[tid] = Wih[tid]; sB[tid] = bih[tid] + bhh[tid]; }
  sWhh[tid] = Whh[tid];  // 256 threads load exactly 256 weights
  __syncthreads();

  const int n = blockIdx.x * 256 + tid;  // chain id = b*S + s
  const float4* xp = (const float4*)(x + (size_t)n * 16);
  float4 xa = xp[0], xb = xp[1], xc = xp[2], xd = xp[3];
  float xv[16] = {xa.x, xa.y, xa.z, xa.w, xb.x, xb.y, xb.z, xb.w,
                  xc.x, xc.y, xc.z, xc.w, xd.x, xd.y, xd.z, xd.w};
  float h[8] = {0, 0, 0, 0, 0, 0, 0, 0};
  float c[8] = {0, 0, 0, 0, 0, 0, 0, 0};

#pragma unroll
  for (int t = 0; t < 16; ++t) {
    float g[32];
#pragma unroll
    for (int r = 0; r < 32; ++r) {
      float a = fmaf(sWih[r], xv[t], sB[r]);
#pragma unroll
      for (int k = 0; k < 8; ++k) a = fmaf(sWhh[r * 8 + k], h[k], a);
      g[r] = a;
    }
#pragma unroll
    for (int k = 0; k < 8; ++k) {
      float iv = fsig(g[k]);
      float fv = fsig(g[8 + k]);
      float gv = ftanh_(g[16 + k]);
      float ov = fsig(g[24 + k]);
      c[k] = fmaf(fv, c[k], iv * gv);
      h[k] = ov * ftanh_(c[k]);
    }
  }
  float4* op = (float4*)(h1 + (size_t)n * 8);
  op[0] = make_float4(h[0], h[1], h[2], h[3]);
  op[1] = make_float4(h[4], h[5], h[6], h[7]);
}

// ---------------------------------------------------------------------------
// Layer 2: B=256 independent recurrences -> 1 block per batch element.
// 512 threads: thread g owns gate-row g (W_hh2 row in 128 VGPRs).
// h (128) + gate activations (512) in LDS; c state in registers (g<128).
// Whole h1[b] slice (32 KB) staged to LDS once -> no global traffic in loop.
// Dense head (128->64->1) fused as epilogue on wave 0.
// ---------------------------------------------------------------------------
__global__ __launch_bounds__(512, 2) void lstm2_kernel(
    const float* __restrict__ h1, const float* __restrict__ Wih,
    const float* __restrict__ Whh, const float* __restrict__ bih,
    const float* __restrict__ bhh, const float* __restrict__ W1,
    const float* __restrict__ b1, const float* __restrict__ W2,
    const float* __restrict__ b2, float* __restrict__ out) {
  __shared__ float sX[1024 * 8];  // 32 KB: this batch's layer-1 outputs
  __shared__ float sH[128];
  __shared__ float sG[512];
  const int b = blockIdx.x;
  const int g = threadIdx.x;

  {  // coalesced stage of h1[b, :, :] into LDS
    const float4* src = (const float4*)(h1 + (size_t)b * 8192);
    float4* dst = (float4*)sX;
#pragma unroll
    for (int i = 0; i < 4; ++i) dst[g + i * 512] = src[g + i * 512];
  }

  float wh[128];
#pragma unroll
  for (int k = 0; k < 32; ++k)
    *(float4*)&wh[k * 4] = *(const float4*)&Whh[(size_t)g * 128 + k * 4];
  float wi[8];
  *(float4*)&wi[0] = *(const float4*)&Wih[g * 8];
  *(float4*)&wi[4] = *(const float4*)&Wih[g * 8 + 4];
  const float bias = bih[g] + bhh[g];

  float c = 0.f;
  if (g < 128) sH[g] = 0.f;
  const bool is_g_gate = (g >= 256) && (g < 384);  // wave-uniform
  __syncthreads();

  for (int t = 0; t < 1024; ++t) {
    const float* xt = &sX[t * 8];
    float a0 = bias, a1 = 0.f, a2 = 0.f, a3 = 0.f;
#pragma unroll
    for (int j = 0; j < 8; ++j) a0 = fmaf(wi[j], xt[j], a0);
#pragma unroll
    for (int k = 0; k < 128; k += 4) {  // broadcast LDS reads (same addr)
      a0 = fmaf(wh[k + 0], sH[k + 0], a0);
      a1 = fmaf(wh[k + 1], sH[k + 1], a1);
      a2 = fmaf(wh[k + 2], sH[k + 2], a2);
      a3 = fmaf(wh[k + 3], sH[k + 3], a3);
    }
    float acc = (a0 + a1) + (a2 + a3);
    sG[g] = is_g_gate ? ftanh_(acc) : fsig(acc);
    __syncthreads();
    if (g < 128) {
      float iv = sG[g], fv = sG[128 + g], gv = sG[256 + g], ov = sG[384 + g];
      c = fmaf(fv, c, iv * gv);
      sH[g] = ov * ftanh_(c);
    }
    __syncthreads();
  }

  // Epilogue: out[b] = (h @ W1.T + b1) @ W2.T + b2, on wave 0.
  if (g < 64) {
    float a = b1[g];
#pragma unroll
    for (int k = 0; k < 128; ++k) a = fmaf(W1[g * 128 + k], sH[k], a);
    float v = a * W2[g];
#pragma unroll
    for (int off = 32; off > 0; off >>= 1) v += __shfl_down(v, off);
    if (g == 0) out[b] = v + b2[0];
  }
}

extern "C" void kernel_launch(void* const* d_in, const int* in_sizes, int n_in,
                              void* d_out, int out_size, void* d_ws, size_t ws_size,
                              hipStream_t stream) {
  const float* x    = (const float*)d_in[0];
  // d_in[1] is the unused python scalar `data`
  const float* Wih1 = (const float*)d_in[2];
  const float* Whh1 = (const float*)d_in[3];
  const float* bih1 = (const float*)d_in[4];
  const float* bhh1 = (const float*)d_in[5];
  const float* Wih2 = (const float*)d_in[6];
  const float* Whh2 = (const float*)d_in[7];
  const float* bih2 = (const float*)d_in[8];
  const float* bhh2 = (const float*)d_in[9];
  const float* W1   = (const float*)d_in[10];
  const float* b1   = (const float*)d_in[11];
  const float* W2   = (const float*)d_in[12];
  const float* b2   = (const float*)d_in[13];
  float* out = (float*)d_out;

  float* h1 = (float*)d_ws;  // 256*1024*8 fp32 = 8 MB scratch

  lstm1_kernel<<<1024, 256, 0, stream>>>(x, Wih1, Whh1, bih1, bhh1, h1);
  lstm2_kernel<<<256, 512, 0, stream>>>(h1, Wih2, Whh2, bih2, bhh2,
                                        W1, b1, W2, b2, out);
}